// Round 4
// baseline (1534.905 us; speedup 1.0000x reference)
//
#include <hip/hip_runtime.h>
#include <cstdint>
#include <cstddef>

#define B_ 128
#define T_ 8192
#define F_ 10
#define F1_ 8
#define H1_ 8
#define H2_ 7
#define K_ 16
#define CHUNK 128
#define NC (T_/CHUNK)   // 64

#define LOG2E 1.4426950408889634f

__device__ __forceinline__ float exp2_fast(float x){ float r; asm("v_exp_f32 %0, %1" : "=v"(r) : "v"(x)); return r; }
__device__ __forceinline__ float rcp_fast(float x){ float r; asm("v_rcp_f32 %0, %1" : "=v"(r) : "v"(x)); return r; }
template<int CTRL>
__device__ __forceinline__ float dppf(float x){
  return __int_as_float(__builtin_amdgcn_update_dpp(0, __float_as_int(x), CTRL, 0xF, 0xF, true));
}
// xor8 within each 16-lane row (row_ror:8; 8 = half-row -> direction-proof)
__device__ __forceinline__ float ror8(float x){ return dppf<0x128>(x); }
typedef int v2i_t __attribute__((ext_vector_type(2)));
// lane L receives value from lane L^32; orientation-proof via bitwise xor3
__device__ __forceinline__ float swap32(float y){
  int yi = __float_as_int(y);
  v2i_t r = __builtin_amdgcn_permlane32_swap(yi, yi, false, false);
  return __int_as_float(r.x ^ r.y ^ yi);
}

// ---------------- Kernel 1: precompute LSTM1 gate inputs (pre-scaled) ------
__global__ __launch_bounds__(256) void k1_pre(const float* __restrict__ x,
    const float* __restrict__ conv_w, const float* __restrict__ conv_b,
    const float* __restrict__ w_ih1, const float* __restrict__ b_ih1,
    const float* __restrict__ b_hh1, float* __restrict__ g1pre)
{
  int g8 = threadIdx.x >> 3;
  int gl = threadIdx.x & 7;
  size_t idx = (size_t)blockIdx.x*32 + g8;    // (b*T + t)
  const float* xp = x + idx*F_;
  float xv[F_];
  #pragma unroll
  for (int f=0; f<F_; ++f) xv[f] = xp[f];
  float enc[F1_];
  #pragma unroll
  for (int o=0;o<F1_;++o){
    float a = conv_b[o];
    #pragma unroll
    for (int f=0;f<F_;++f) a += conv_w[o*F_+f]*xv[f];
    enc[o] = a > 0.f ? a : 0.01f*a;   // leaky_relu 0.01
  }
  float4 out;
  #pragma unroll
  for (int q=0;q<4;++q){
    int row = gl*4+q;
    float a = b_ih1[row]+b_hh1[row];
    #pragma unroll
    for (int o=0;o<F1_;++o) a += w_ih1[row*F1_+o]*enc[o];
    float s = (row>=16 && row<24) ? (-2.f*LOG2E) : (-LOG2E);  // fold act scale
    (&out.x)[q] = a*s;
  }
  ((float4*)(g1pre + idx*32))[gl] = out;
}

// ---------------- Kernel 2: wave-specialized stacked LSTMs -----------------
// Block = 2 waves. Wave 0: LSTM1 (producer), wave 1: LSTM2 (consumer).
// tanh(h1) streams through a contiguous 512-step (4-chunk) LDS ring.
// Gate lane layout (xor-partner scheme, both waves):
//   i: lanes 0-7, g: 8-15, f: 32-39, o: 40-47 (dups at +16 per 32-half).
// All-lane algebra: a=y, b=ror8(y)[xor8], sa=swap32(y)[xor32], sb=ror8(sa)[xor40]
//   IG = up ? sa*sb : a*b ; F = up ? (c2?b:a) : (c2?sb:sa) ; O = up ? (c2?a:b) : (c2?sa:sb)
//   (verified per lane-class: i,g,f,o all yield sig(f), sig(o), sig(i)*gact)
// State cs = -2*log2e * c  (g-gate emits -2k*tanh via A=-4k, D=+2k).
__global__ __launch_bounds__(128,1) void k2_lstm(
    const float* __restrict__ g1pre,
    const float* __restrict__ w_hh1,
    const float* __restrict__ w_ih2, const float* __restrict__ w_hh2,
    const float* __restrict__ b_ih2, const float* __restrict__ b_hh2,
    float* __restrict__ zout)
{
  __shared__ float ring[512*8];   // 16 KB: [t mod 512][8]
  const int b = blockIdx.x;
  const int tid = threadIdx.x;
  const int wv = tid >> 6;
  const int lane = tid & 63;
  const int u = lane & 7;
  const int c2 = (lane >> 3) & 1;
  const int up = (lane >> 5) & 1;
  const int gi = up ? (c2 ? 3 : 1) : (c2 ? 2 : 0);   // PyTorch gate idx i,f,g,o
  const bool isg = (!up && c2);
  const float Sx = isg ? (-2.f*LOG2E) : (-LOG2E);
  const float A_ = isg ? (-4.f*LOG2E) : 1.f;
  const float D_ = isg ? ( 2.f*LOG2E) : 0.f;

  if (wv == 0){
    // ---------------- Wave A: LSTM1 ----------------
    const int prow = gi*8 + u;
    float wp[8];
    #pragma unroll
    for (int m=0;m<8;++m) wp[m] = w_hh1[prow*8 + (u^m)] * Sx;
    const float* pA = g1pre + (size_t)b*T_*32 + prow;
    float pf[16];
    #pragma unroll
    for (int i=0;i<16;++i) pf[i] = pA[(size_t)i*32];
    float hq=0.f, csq=0.f;
    for (int c=0;c<NC;++c){
      asm volatile("s_waitcnt lgkmcnt(0)\ns_barrier" ::: "memory");
      for (int s0=0;s0<CHUNK;s0+=16){
        #pragma unroll
        for (int si=0;si<16;++si){
          const int s = s0+si;
          const int t = c*CHUNK+s;
          float pre = pf[s&15];
          int tn = t+16; if (tn>T_-1) tn=T_-1;
          pf[s&15] = pA[(size_t)tn*32];
          float x1 = dppf<0xB1>(hq);     // h[u^1]
          float x2 = dppf<0x4E>(hq);     // h[u^2]
          float x4 = dppf<0x124>(hq);    // h[u^4] (ror4 on 8-periodic)
          float x3 = dppf<0xB1>(x2);     // h[u^3]
          float x5 = dppf<0x124>(x1);    // h[u^5]
          float x6 = dppf<0x124>(x2);    // h[u^6]
          float x7 = dppf<0x124>(x3);    // h[u^7]
          float a0 = fmaf(wp[0], hq, pre);
          float a1 = wp[1]*x1;
          float a2 = wp[2]*x2;
          float a3 = wp[3]*x3;
          a0 = fmaf(wp[4], x4, a0);
          a1 = fmaf(wp[5], x5, a1);
          a2 = fmaf(wp[6], x6, a2);
          a3 = fmaf(wp[7], x7, a3);
          float g = (a0+a1)+(a2+a3);
          float e = exp2_fast(g);
          float y = fmaf(A_, rcp_fast(1.f+e), D_);
          float b8 = ror8(y);
          float sa = swap32(y);
          float sb = ror8(sa);
          float p1 = y*b8, p2 = sa*sb;
          float ig = up ? p2 : p1;
          float q1 = c2 ? b8 : y;
          float q2 = c2 ? y  : b8;
          float q3 = c2 ? sb : sa;
          float q4 = c2 ? sa : sb;
          float Fv = up ? q1 : q3;
          float Ov = up ? q2 : q4;
          float cs = fmaf(Fv, csq, ig);
          float e2 = exp2_fast(cs);
          float tc = fmaf(2.f, rcp_fast(1.f+e2), -1.f);
          float hn = Ov*tc;
          csq = cs; hq = hn;
          float e3 = exp2_fast(hn * (-2.f*LOG2E));
          float th = fmaf(2.f, rcp_fast(1.f+e3), -1.f);
          if (lane < 8) ring[((t&511)<<3) + u] = th;
        }
      }
    }
    asm volatile("s_waitcnt lgkmcnt(0)\ns_barrier" ::: "memory");
    asm volatile("s_barrier" ::: "memory");
  } else {
    // ---------------- Wave B: LSTM2 ----------------
    const int r2 = gi*7 + u;
    float wc[8], wb[8]; float pre2 = 0.f;
    #pragma unroll
    for (int j=0;j<8;++j){ wc[j]=0.f; wb[j]=0.f; }
    if (u < 7){
      #pragma unroll
      for (int j=0;j<8;++j) wc[j] = w_ih2[r2*8+j]*Sx;
      #pragma unroll
      for (int m=0;m<8;++m){ int jm = u^m; wb[m] = (jm<7) ? w_hh2[r2*7+jm]*Sx : 0.f; }
      pre2 = (b_ih2[r2]+b_hh2[r2])*Sx;
    }
    float* zb = zout + (size_t)b*T_*H2_;
    float hq=0.f, csq=0.f;
    float4 tl[4], th_[4];
    asm volatile("s_barrier" ::: "memory");   // pairs A before chunk 0
    asm volatile("s_barrier" ::: "memory");   // pairs A before chunk 1 -> chunk 0 ready
    #pragma unroll
    for (int i=0;i<4;++i){
      const float4* pp = (const float4*)&ring[i<<3];
      tl[i] = pp[0]; th_[i] = pp[1];
    }
    for (int cb=2; cb<NC+2; ++cb){
      asm volatile("s_barrier" ::: "memory");
      const int base_t = (cb-2)*CHUNK;
      for (int s0=0;s0<CHUNK;s0+=8){
        #pragma unroll
        for (int si=0;si<8;++si){
          const int s = s0+si;
          const int t = base_t + s;
          float4 lo = tl[s&3], hi = th_[s&3];
          int tp = t+4; if (tp>T_-1) tp=T_-1;
          const float4* pp = (const float4*)&ring[(tp&511)<<3];
          tl[s&3] = pp[0]; th_[s&3] = pp[1];
          // feed-forward part (off the h2 chain)
          float b0 = fmaf(wc[0], lo.x, pre2);
          float b1 = wc[1]*lo.y;
          b0 = fmaf(wc[2], lo.z, b0);
          b1 = fmaf(wc[3], lo.w, b1);
          b0 = fmaf(wc[4], hi.x, b0);
          b1 = fmaf(wc[5], hi.y, b1);
          b0 = fmaf(wc[6], hi.z, b0);
          b1 = fmaf(wc[7], hi.w, b1);
          float x1 = dppf<0xB1>(hq);
          float x2 = dppf<0x4E>(hq);
          float x4 = dppf<0x124>(hq);
          float x3 = dppf<0xB1>(x2);
          float x5 = dppf<0x124>(x1);
          float x6 = dppf<0x124>(x2);
          float x7 = dppf<0x124>(x3);
          float a0 = fmaf(wb[0], hq, b0);
          float a1 = fmaf(wb[1], x1, b1);
          float a2 = wb[2]*x2;
          float a3 = wb[3]*x3;
          a0 = fmaf(wb[4], x4, a0);
          a1 = fmaf(wb[5], x5, a1);
          a2 = fmaf(wb[6], x6, a2);
          a3 = fmaf(wb[7], x7, a3);
          float g = (a0+a1)+(a2+a3);
          float e = exp2_fast(g);
          float y = fmaf(A_, rcp_fast(1.f+e), D_);
          float b8 = ror8(y);
          float sa = swap32(y);
          float sb = ror8(sa);
          float p1 = y*b8, p2 = sa*sb;
          float ig = up ? p2 : p1;
          float q1 = c2 ? b8 : y;
          float q2 = c2 ? y  : b8;
          float q3 = c2 ? sb : sa;
          float q4 = c2 ? sa : sb;
          float Fv = up ? q1 : q3;
          float Ov = up ? q2 : q4;
          float cs = fmaf(Fv, csq, ig);
          float e2 = exp2_fast(cs);
          float tc = fmaf(2.f, rcp_fast(1.f+e2), -1.f);
          float hn = Ov*tc;
          csq = cs; hq = hn;
          float e3 = exp2_fast(hn * (-2.f*LOG2E));
          float z = fmaf(2.f, rcp_fast(1.f+e3), -1.f);
          if (lane < 7) zb[(size_t)t*H2_ + lane] = z;
        }
      }
    }
  }
}

// ---------------- Kernel 3: S[b,k] = sum_t Q[b,t,k] ------------------------
__global__ __launch_bounds__(256) void k3_S(const float* __restrict__ zout,
    const float* __restrict__ centers, float* __restrict__ S)
{
  int b = blockIdx.x; int tid = threadIdx.x;
  float cc[K_]; float cw[K_][H2_];
  #pragma unroll
  for (int k=0;k<K_;++k){ float s=0.f;
    #pragma unroll
    for (int j=0;j<H2_;++j){ float c=centers[k*H2_+j]; cw[k][j]=c; s+=c*c; }
    cc[k]=s; }
  float acc[K_];
  #pragma unroll
  for (int k=0;k<K_;++k) acc[k]=0.f;
  const float* zb = zout + (size_t)b*T_*H2_;
  for (int t=tid; t<T_; t+=256){
    float zv[H2_]; float zz=0.f;
    #pragma unroll
    for (int j=0;j<H2_;++j){ zv[j]=zb[(size_t)t*H2_+j]; zz+=zv[j]*zv[j]; }
    #pragma unroll
    for (int k=0;k<K_;++k){
      float d = zz + cc[k];
      #pragma unroll
      for (int j=0;j<H2_;++j) d -= 2.f*cw[k][j]*zv[j];
      acc[k] += rcp_fast(1.f + d);
    }
  }
  __shared__ float sred[4][K_];
  int wid = tid>>6;
  #pragma unroll
  for (int k=0;k<K_;++k){
    float v = acc[k];
    #pragma unroll
    for (int off=32; off; off>>=1) v += __shfl_down(v, off);
    acc[k]=v;
  }
  if ((tid&63)==0){
    #pragma unroll
    for (int k=0;k<K_;++k) sred[wid][k]=acc[k];
  }
  __syncthreads();
  if (tid < K_){
    S[b*K_+tid] = sred[0][tid]+sred[1][tid]+sred[2][tid]+sred[3][tid];
  }
}

// ---------------- Kernel 4: decoder + fq/fp --------------------------------
__global__ __launch_bounds__(256) void k4_out(const float* __restrict__ zout,
    const float* __restrict__ dec_w, const float* __restrict__ dec_b,
    const float* __restrict__ centers, const float* __restrict__ S,
    float* __restrict__ xr, float* __restrict__ fp, float* __restrict__ fq)
{
  int idx = blockIdx.x*256 + threadIdx.x;
  if (idx >= B_*T_) return;
  int b = idx >> 13;   // /T_
  float zv[H2_]; float zz=0.f;
  const float* zp = zout + (size_t)idx*H2_;
  #pragma unroll
  for (int j=0;j<H2_;++j){ zv[j]=zp[j]; zz+=zv[j]*zv[j]; }
  float2 xo[5];
  #pragma unroll
  for (int f=0; f<F_; ++f){
    float a = dec_b[f];
    #pragma unroll
    for (int c=0;c<H2_;++c) a += zv[c]*dec_w[c*F_+f];
    (&xo[0].x)[f] = a;
  }
  float2* xp2 = (float2*)(xr + (size_t)idx*F_);
  #pragma unroll
  for (int c=0;c<5;++c) xp2[c] = xo[c];

  float Q[K_], P[K_]; float qs=0.f, ps=0.f;
  #pragma unroll
  for (int k=0;k<K_;++k){
    float d = zz;
    #pragma unroll
    for (int j=0;j<H2_;++j){ float c=centers[k*H2_+j]; d += c*c - 2.f*c*zv[j]; }
    float q = rcp_fast(1.f+d);
    Q[k]=q; qs+=q;
    float p = q*q*rcp_fast(S[b*K_+k]);
    P[k]=p; ps+=p;
  }
  float iq = rcp_fast(qs), ip = rcp_fast(ps);
  float4* fqp = (float4*)(fq + (size_t)idx*K_);
  float4* fpp = (float4*)(fp + (size_t)idx*K_);
  #pragma unroll
  for (int c=0;c<4;++c){
    float4 vq, vp;
    vq.x=Q[4*c+0]*iq; vq.y=Q[4*c+1]*iq; vq.z=Q[4*c+2]*iq; vq.w=Q[4*c+3]*iq;
    vp.x=P[4*c+0]*ip; vp.y=P[4*c+1]*ip; vp.z=P[4*c+2]*ip; vp.w=P[4*c+3]*ip;
    fqp[c]=vq; fpp[c]=vp;
  }
}

extern "C" void kernel_launch(void* const* d_in, const int* in_sizes, int n_in,
                              void* d_out, int out_size, void* d_ws, size_t ws_size,
                              hipStream_t stream)
{
  (void)in_sizes; (void)n_in; (void)out_size; (void)ws_size;
  const float* x      = (const float*)d_in[0];
  const float* conv_w = (const float*)d_in[1];
  const float* conv_b = (const float*)d_in[2];
  const float* w_ih1  = (const float*)d_in[3];
  const float* w_hh1  = (const float*)d_in[4];
  const float* b_ih1  = (const float*)d_in[5];
  const float* b_hh1  = (const float*)d_in[6];
  const float* w_ih2  = (const float*)d_in[7];
  const float* w_hh2  = (const float*)d_in[8];
  const float* b_ih2  = (const float*)d_in[9];
  const float* b_hh2  = (const float*)d_in[10];
  const float* dec_w  = (const float*)d_in[11];
  const float* dec_b  = (const float*)d_in[12];
  const float* centers= (const float*)d_in[13];

  float* out = (float*)d_out;
  float* z   = out;                              // [B,T,7]
  float* xr  = out + (size_t)B_*T_*H2_;          // [B,T,10]
  float* fp  = xr  + (size_t)B_*T_*F_;           // [B,T,16]
  float* fq  = fp  + (size_t)B_*T_*K_;           // [B,T,16]

  float* g1pre = (float*)d_ws;                   // 128 MB: [B,T,32] (pre-scaled)
  float* S     = (float*)d_ws;                   // reused after k2: [B,K]

  k1_pre<<<dim3((B_*T_)/32), dim3(256), 0, stream>>>(x, conv_w, conv_b, w_ih1, b_ih1, b_hh1, g1pre);
  k2_lstm<<<dim3(B_), dim3(128), 0, stream>>>(g1pre, w_hh1, w_ih2, w_hh2, b_ih2, b_hh2, z);
  k3_S<<<dim3(B_), dim3(256), 0, stream>>>(z, centers, S);
  k4_out<<<dim3((B_*T_)/256), dim3(256), 0, stream>>>(z, dec_w, dec_b, centers, S, xr, fp, fq);
}

// Round 5
// 1192.228 us; speedup vs baseline: 1.2874x; 1.2874x over previous
//
#include <hip/hip_runtime.h>
#include <cstdint>
#include <cstddef>

#define B_ 128
#define T_ 8192
#define F_ 10
#define F1_ 8
#define H1_ 8
#define H2_ 7
#define K_ 16
#define CHUNK 64
#define NC (T_/CHUNK)   // 128
#define RMASK 255       // 4-chunk ring (256 rows)

#define LOG2E 1.4426950408889634f

__device__ __forceinline__ float exp2_fast(float x){ float r; asm("v_exp_f32 %0, %1" : "=v"(r) : "v"(x)); return r; }
__device__ __forceinline__ float rcp_fast(float x){ float r; asm("v_rcp_f32 %0, %1" : "=v"(r) : "v"(x)); return r; }
template<int CTRL>
__device__ __forceinline__ float dppf(float x){
  return __int_as_float(__builtin_amdgcn_update_dpp(0, __float_as_int(x), CTRL, 0xF, 0xF, true));
}
// xor8 within each 16-lane row (row_ror:8) -- validated r2-r4
__device__ __forceinline__ float ror8(float x){ return dppf<0x128>(x); }
typedef int v2i_t __attribute__((ext_vector_type(2)));

// ---------------- Kernel 1: precompute LSTM1 gate inputs (pre-scaled) ------
__global__ __launch_bounds__(256) void k1_pre(const float* __restrict__ x,
    const float* __restrict__ conv_w, const float* __restrict__ conv_b,
    const float* __restrict__ w_ih1, const float* __restrict__ b_ih1,
    const float* __restrict__ b_hh1, float* __restrict__ g1pre)
{
  int g8 = threadIdx.x >> 3;
  int gl = threadIdx.x & 7;
  size_t idx = (size_t)blockIdx.x*32 + g8;    // (b*T + t)
  const float* xp = x + idx*F_;
  float xv[F_];
  #pragma unroll
  for (int f=0; f<F_; ++f) xv[f] = xp[f];
  float enc[F1_];
  #pragma unroll
  for (int o=0;o<F1_;++o){
    float a = conv_b[o];
    #pragma unroll
    for (int f=0;f<F_;++f) a += conv_w[o*F_+f]*xv[f];
    enc[o] = a > 0.f ? a : 0.01f*a;   // leaky_relu 0.01
  }
  float4 out;
  #pragma unroll
  for (int q=0;q<4;++q){
    int row = gl*4+q;
    float a = b_ih1[row]+b_hh1[row];
    #pragma unroll
    for (int o=0;o<F1_;++o) a += w_ih1[row*F1_+o]*enc[o];
    float s = (row>=16 && row<24) ? (-2.f*LOG2E) : (-LOG2E);  // fold act scale
    (&out.x)[q] = a*s;
  }
  ((float4*)(g1pre + idx*32))[gl] = out;
}

// ---------------- Kernel 2: wave-specialized stacked LSTMs -----------------
// Block = 2 waves. Wave 0: LSTM1 (producer), wave 1: LSTM2 (consumer).
// tanh(h1) streams through a 256-row x 64-wide LDS ring (64KB), rows written
// by ALL 64 lanes (no exec mask), read as 2 float4 by wave B.
// Gate lane blocks (lane>>3): [i, g, i, g | f, o, f, o]; unit u = lane&7.
// After activation y = [si, gt, si, gt | sf, so, sf, so] (gt = -2k*tanh):
//   pair = permlane32_swap(y,y): pair.x = [lo|lo] = (c2? gt : si)
//                                pair.y = [hi|hi] = (c2? so : sf)
//   IG = pair.x * ror8(pair.x)   (= si*gt in ALL lanes, select-free)
//   HR = ror8(pair.y); Fv = c2? HR : pair.y; Ov = c2? pair.y : HR
// State cs = -2*log2e*c; h replicated as h[u] in all 64 lanes.
__global__ __launch_bounds__(128,1) void k2_lstm(
    const float* __restrict__ g1pre,
    const float* __restrict__ w_hh1,
    const float* __restrict__ w_ih2, const float* __restrict__ w_hh2,
    const float* __restrict__ b_ih2, const float* __restrict__ b_hh2,
    float* __restrict__ zout)
{
  __shared__ float ring[256*64];   // 64 KB exactly
  const int b = blockIdx.x;
  const int tid = threadIdx.x;
  const int wv = tid >> 6;
  const int lane = tid & 63;
  const int u = lane & 7;
  const bool c2 = (lane >> 3) & 1;
  const bool up = (lane >> 5) & 1;
  const bool isg = (c2 && !up);
  const float Sx = isg ? (-2.f*LOG2E) : (-LOG2E);
  const float A_ = isg ? (-4.f*LOG2E) : 1.f;
  const float D_ = isg ? ( 2.f*LOG2E) : 0.f;
  // gate row within the 4H block: i|f|g|o = 0-7|8-15|16-23|24-31 (H=8)
  const int prow = u + (c2 ? 16 : 0) + (up ? 8 : 0);

  if (wv == 0){
    // ---------------- Wave A: LSTM1 ----------------
    float wp[8];
    #pragma unroll
    for (int m=0;m<8;++m) wp[m] = w_hh1[prow*8 + (u^m)] * Sx;
    const float* pA = g1pre + (size_t)b*T_*32 + prow;
    float pf[16];
    #pragma unroll
    for (int i=0;i<16;++i) pf[i] = pA[(size_t)i*32];
    float hq=0.f, csq=0.f;
    for (int c=0;c<NC;++c){
      asm volatile("s_waitcnt lgkmcnt(0)\ns_barrier" ::: "memory");
      float* rowbase0 = &ring[((c*CHUNK)&RMASK)<<6];
      for (int s0=0;s0<CHUNK;s0+=16){
        #pragma unroll
        for (int si=0;si<16;++si){
          const int s = s0+si;
          const int t = c*CHUNK+s;
          float pre = pf[s&15];
          int tn = t+16; if (tn>T_-1) tn=T_-1;
          pf[s&15] = pA[(size_t)tn*32];
          // gather h[u^m] (h replicated in all lanes)
          float x1 = dppf<0xB1>(hq);
          float x2 = dppf<0x4E>(hq);
          float x4 = dppf<0x124>(hq);
          float x3 = dppf<0xB1>(x2);
          float x5 = dppf<0x124>(x1);
          float x6 = dppf<0x124>(x2);
          float x7 = dppf<0x124>(x3);
          float a0 = fmaf(wp[0], hq, pre);
          float a1 = wp[1]*x1;
          float a2 = wp[2]*x2;
          float a3 = wp[3]*x3;
          a0 = fmaf(wp[4], x4, a0);
          a1 = fmaf(wp[5], x5, a1);
          a2 = fmaf(wp[6], x6, a2);
          a3 = fmaf(wp[7], x7, a3);
          float g = (a0+a1)+(a2+a3);
          float e = exp2_fast(g);
          float y = fmaf(A_, rcp_fast(1.f+e), D_);
          v2i_t pr = __builtin_amdgcn_permlane32_swap(__float_as_int(y), __float_as_int(y), false, false);
          float lov = __int_as_float(pr.x);     // [si,gt] pattern, all lanes
          float hiv = __int_as_float(pr.y);     // [sf,so] pattern, all lanes
          float IG = lov * ror8(lov);           // si*gt everywhere
          float HR = ror8(hiv);
          float Fv = c2 ? HR : hiv;             // sf
          float Ov = c2 ? hiv : HR;             // so
          float cs = fmaf(Fv, csq, IG);
          float e2 = exp2_fast(cs);
          float tc = fmaf(2.f, rcp_fast(1.f+e2), -1.f);
          float hn = Ov*tc;
          csq = cs; hq = hn;
          float e3 = exp2_fast(hn * (-2.f*LOG2E));
          float th = fmaf(2.f, rcp_fast(1.f+e3), -1.f);
          ring[(((t&RMASK))<<6) + lane] = th;   // all 64 lanes, no exec mask
        }
      }
      (void)rowbase0;
    }
    asm volatile("s_waitcnt lgkmcnt(0)\ns_barrier" ::: "memory");
    asm volatile("s_barrier" ::: "memory");
  } else {
    // ---------------- Wave B: LSTM2 ----------------
    const int r2 = u + (c2 ? 14 : 0) + (up ? 7 : 0);   // i|f|g|o = 0-6|7-13|14-20|21-27
    float wc[8], wb[8]; float pre2 = 0.f;
    #pragma unroll
    for (int j=0;j<8;++j){ wc[j]=0.f; wb[j]=0.f; }
    if (u < 7){
      #pragma unroll
      for (int j=0;j<8;++j) wc[j] = w_ih2[r2*8+j]*Sx;
      #pragma unroll
      for (int m=0;m<8;++m){ int jm = u^m; wb[m] = (jm<7) ? w_hh2[r2*7+jm]*Sx : 0.f; }
      pre2 = (b_ih2[r2]+b_hh2[r2])*Sx;
    }
    float* zb = zout + (size_t)b*T_*H2_;
    float hq=0.f, csq=0.f;
    float4 tl[4], th_[4];
    asm volatile("s_barrier" ::: "memory");   // pairs A chunk 0
    asm volatile("s_barrier" ::: "memory");   // pairs A chunk 1 -> chunk 0 ready
    #pragma unroll
    for (int i=0;i<4;++i){
      const float4* pp = (const float4*)&ring[i<<6];
      tl[i] = pp[0]; th_[i] = pp[1];
    }
    float zs[8];
    const int srow = lane >> 3;      // step-within-burst this lane stores
    for (int cb=2; cb<NC+2; ++cb){
      asm volatile("s_barrier" ::: "memory");
      const int base_t = (cb-2)*CHUNK;
      for (int s0=0;s0<CHUNK;s0+=8){
        #pragma unroll
        for (int si=0;si<8;++si){
          const int s = s0+si;
          const int t = base_t + s;
          float4 lo = tl[s&3], hi = th_[s&3];
          int tp = t+4; if (tp>T_-1) tp=T_-1;
          const float4* pp = (const float4*)&ring[(tp&RMASK)<<6];
          tl[s&3] = pp[0]; th_[s&3] = pp[1];
          // feed-forward part (off the h2 chain)
          float b0 = fmaf(wc[0], lo.x, pre2);
          float b1 = wc[1]*lo.y;
          b0 = fmaf(wc[2], lo.z, b0);
          b1 = fmaf(wc[3], lo.w, b1);
          b0 = fmaf(wc[4], hi.x, b0);
          b1 = fmaf(wc[5], hi.y, b1);
          b0 = fmaf(wc[6], hi.z, b0);
          b1 = fmaf(wc[7], hi.w, b1);
          float x1 = dppf<0xB1>(hq);
          float x2 = dppf<0x4E>(hq);
          float x4 = dppf<0x124>(hq);
          float x3 = dppf<0xB1>(x2);
          float x5 = dppf<0x124>(x1);
          float x6 = dppf<0x124>(x2);
          float x7 = dppf<0x124>(x3);
          float a0 = fmaf(wb[0], hq, b0);
          float a1 = fmaf(wb[1], x1, b1);
          float a2 = wb[2]*x2;
          float a3 = wb[3]*x3;
          a0 = fmaf(wb[4], x4, a0);
          a1 = fmaf(wb[5], x5, a1);
          a2 = fmaf(wb[6], x6, a2);
          a3 = fmaf(wb[7], x7, a3);
          float g = (a0+a1)+(a2+a3);
          float e = exp2_fast(g);
          float y = fmaf(A_, rcp_fast(1.f+e), D_);
          v2i_t pr = __builtin_amdgcn_permlane32_swap(__float_as_int(y), __float_as_int(y), false, false);
          float lov = __int_as_float(pr.x);
          float hiv = __int_as_float(pr.y);
          float IG = lov * ror8(lov);
          float HR = ror8(hiv);
          float Fv = c2 ? HR : hiv;
          float Ov = c2 ? hiv : HR;
          float cs = fmaf(Fv, csq, IG);
          float e2 = exp2_fast(cs);
          float tc = fmaf(2.f, rcp_fast(1.f+e2), -1.f);
          float hn = Ov*tc;
          csq = cs; hq = hn;
          float e3 = exp2_fast(hn * (-2.f*LOG2E));
          zs[si] = fmaf(2.f, rcp_fast(1.f+e3), -1.f);   // z, replicated z[u]
        }
        // burst store: lane L -> step srow=L>>3, unit u=L&7 (u<7)
        float v0 = ((lane>>3)&1) ? zs[1] : zs[0];
        float v1 = ((lane>>3)&1) ? zs[3] : zs[2];
        float v2 = ((lane>>3)&1) ? zs[5] : zs[4];
        float v3 = ((lane>>3)&1) ? zs[7] : zs[6];
        float w0 = ((lane>>4)&1) ? v1 : v0;
        float w1 = ((lane>>4)&1) ? v3 : v2;
        float zo = ((lane>>5)&1) ? w1 : w0;
        if (u < 7) zb[(size_t)(base_t + s0 + srow)*H2_ + u] = zo;
      }
    }
  }
}

// ---------------- Kernel 3: S[b,k] = sum_t Q[b,t,k] ------------------------
__global__ __launch_bounds__(256) void k3_S(const float* __restrict__ zout,
    const float* __restrict__ centers, float* __restrict__ S)
{
  int b = blockIdx.x; int tid = threadIdx.x;
  float cc[K_]; float cw[K_][H2_];
  #pragma unroll
  for (int k=0;k<K_;++k){ float s=0.f;
    #pragma unroll
    for (int j=0;j<H2_;++j){ float c=centers[k*H2_+j]; cw[k][j]=c; s+=c*c; }
    cc[k]=s; }
  float acc[K_];
  #pragma unroll
  for (int k=0;k<K_;++k) acc[k]=0.f;
  const float* zb = zout + (size_t)b*T_*H2_;
  for (int t=tid; t<T_; t+=256){
    float zv[H2_]; float zz=0.f;
    #pragma unroll
    for (int j=0;j<H2_;++j){ zv[j]=zb[(size_t)t*H2_+j]; zz+=zv[j]*zv[j]; }
    #pragma unroll
    for (int k=0;k<K_;++k){
      float d = zz + cc[k];
      #pragma unroll
      for (int j=0;j<H2_;++j) d -= 2.f*cw[k][j]*zv[j];
      acc[k] += rcp_fast(1.f + d);
    }
  }
  __shared__ float sred[4][K_];
  int wid = tid>>6;
  #pragma unroll
  for (int k=0;k<K_;++k){
    float v = acc[k];
    #pragma unroll
    for (int off=32; off; off>>=1) v += __shfl_down(v, off);
    acc[k]=v;
  }
  if ((tid&63)==0){
    #pragma unroll
    for (int k=0;k<K_;++k) sred[wid][k]=acc[k];
  }
  __syncthreads();
  if (tid < K_){
    S[b*K_+tid] = sred[0][tid]+sred[1][tid]+sred[2][tid]+sred[3][tid];
  }
}

// ---------------- Kernel 4: decoder + fq/fp --------------------------------
__global__ __launch_bounds__(256) void k4_out(const float* __restrict__ zout,
    const float* __restrict__ dec_w, const float* __restrict__ dec_b,
    const float* __restrict__ centers, const float* __restrict__ S,
    float* __restrict__ xr, float* __restrict__ fp, float* __restrict__ fq)
{
  int idx = blockIdx.x*256 + threadIdx.x;
  if (idx >= B_*T_) return;
  int b = idx >> 13;   // /T_
  float zv[H2_]; float zz=0.f;
  const float* zp = zout + (size_t)idx*H2_;
  #pragma unroll
  for (int j=0;j<H2_;++j){ zv[j]=zp[j]; zz+=zv[j]*zv[j]; }
  float2 xo[5];
  #pragma unroll
  for (int f=0; f<F_; ++f){
    float a = dec_b[f];
    #pragma unroll
    for (int c=0;c<H2_;++c) a += zv[c]*dec_w[c*F_+f];
    (&xo[0].x)[f] = a;
  }
  float2* xp2 = (float2*)(xr + (size_t)idx*F_);
  #pragma unroll
  for (int c=0;c<5;++c) xp2[c] = xo[c];

  float Q[K_], P[K_]; float qs=0.f, ps=0.f;
  #pragma unroll
  for (int k=0;k<K_;++k){
    float d = zz;
    #pragma unroll
    for (int j=0;j<H2_;++j){ float c=centers[k*H2_+j]; d += c*c - 2.f*c*zv[j]; }
    float q = rcp_fast(1.f+d);
    Q[k]=q; qs+=q;
    float p = q*q*rcp_fast(S[b*K_+k]);
    P[k]=p; ps+=p;
  }
  float iq = rcp_fast(qs), ip = rcp_fast(ps);
  float4* fqp = (float4*)(fq + (size_t)idx*K_);
  float4* fpp = (float4*)(fp + (size_t)idx*K_);
  #pragma unroll
  for (int c=0;c<4;++c){
    float4 vq, vp;
    vq.x=Q[4*c+0]*iq; vq.y=Q[4*c+1]*iq; vq.z=Q[4*c+2]*iq; vq.w=Q[4*c+3]*iq;
    vp.x=P[4*c+0]*ip; vp.y=P[4*c+1]*ip; vp.z=P[4*c+2]*ip; vp.w=P[4*c+3]*ip;
    fqp[c]=vq; fpp[c]=vp;
  }
}

extern "C" void kernel_launch(void* const* d_in, const int* in_sizes, int n_in,
                              void* d_out, int out_size, void* d_ws, size_t ws_size,
                              hipStream_t stream)
{
  (void)in_sizes; (void)n_in; (void)out_size; (void)ws_size;
  const float* x      = (const float*)d_in[0];
  const float* conv_w = (const float*)d_in[1];
  const float* conv_b = (const float*)d_in[2];
  const float* w_ih1  = (const float*)d_in[3];
  const float* w_hh1  = (const float*)d_in[4];
  const float* b_ih1  = (const float*)d_in[5];
  const float* b_hh1  = (const float*)d_in[6];
  const float* w_ih2  = (const float*)d_in[7];
  const float* w_hh2  = (const float*)d_in[8];
  const float* b_ih2  = (const float*)d_in[9];
  const float* b_hh2  = (const float*)d_in[10];
  const float* dec_w  = (const float*)d_in[11];
  const float* dec_b  = (const float*)d_in[12];
  const float* centers= (const float*)d_in[13];

  float* out = (float*)d_out;
  float* z   = out;                              // [B,T,7]
  float* xr  = out + (size_t)B_*T_*H2_;          // [B,T,10]
  float* fp  = xr  + (size_t)B_*T_*F_;           // [B,T,16]
  float* fq  = fp  + (size_t)B_*T_*K_;           // [B,T,16]

  float* g1pre = (float*)d_ws;                   // 128 MB: [B,T,32] (pre-scaled)
  float* S     = (float*)d_ws;                   // reused after k2: [B,K]

  k1_pre<<<dim3((B_*T_)/32), dim3(256), 0, stream>>>(x, conv_w, conv_b, w_ih1, b_ih1, b_hh1, g1pre);
  k2_lstm<<<dim3(B_), dim3(128), 0, stream>>>(g1pre, w_hh1, w_ih2, w_hh2, b_ih2, b_hh2, z);
  k3_S<<<dim3(B_), dim3(256), 0, stream>>>(z, centers, S);
  k4_out<<<dim3((B_*T_)/256), dim3(256), 0, stream>>>(z, dec_w, dec_b, centers, S, xr, fp, fq);
}